// Round 3
// baseline (1358.413 us; speedup 1.0000x reference)
//
#include <hip/hip_runtime.h>
#include <hip/hip_bf16.h>
#include <cstdint>
#include <cstddef>

// Problem constants
#define DMODEL 1024
#define DINNER 2048
#define DSTATE 16
#define DCONV  4
#define DTRANK 64
#define NBATCH 2
#define LSEQ   2048
#define MROWS  (NBATCH*LSEQ)   // 4096

// Scan chunking
#define NCH  16
#define CLEN 128

typedef __bf16 bf16x8 __attribute__((ext_vector_type(8)));
typedef float  f32x4  __attribute__((ext_vector_type(4)));

__device__ __forceinline__ float bf2f(__hip_bfloat16 v) { return __bfloat162float(v); }

__device__ __forceinline__ void gll16(const void* g, void* l) {
  __builtin_amdgcn_global_load_lds((const __attribute__((address_space(1))) void*)g,
                                   (__attribute__((address_space(3))) void*)l, 16, 0, 0);
}

// ---------------- f32 -> bf16 cast (weights) ----------------
__global__ void cast_f2b(const float* __restrict__ src, __hip_bfloat16* __restrict__ dst, int n) {
  int i = (blockIdx.x * 256 + threadIdx.x) * 4;
  if (i + 3 < n) {
    float4 v = *(const float4*)(src + i);
    dst[i + 0] = __float2bfloat16(v.x);
    dst[i + 1] = __float2bfloat16(v.y);
    dst[i + 2] = __float2bfloat16(v.z);
    dst[i + 3] = __float2bfloat16(v.w);
  } else {
    for (int j = i; j < n; ++j) dst[j] = __float2bfloat16(src[j]);
  }
}

// ---------------- LayerNorm: x (4096x1024 f32) -> hn (bf16) ----------------
__global__ void ln_kernel(const float* __restrict__ x,
                          const float* __restrict__ g,
                          const float* __restrict__ b,
                          __hip_bfloat16* __restrict__ hn) {
  const int r = blockIdx.x;
  const int t = threadIdx.x;           // 256 threads
  float v[4];
  float s = 0.f, ss = 0.f;
  #pragma unroll
  for (int i = 0; i < 4; ++i) {
    v[i] = x[(size_t)r * DMODEL + t + i * 256];
    s += v[i]; ss += v[i] * v[i];
  }
  #pragma unroll
  for (int o = 32; o >= 1; o >>= 1) { s += __shfl_xor(s, o); ss += __shfl_xor(ss, o); }
  __shared__ float rs[4], rss[4];
  if ((t & 63) == 0) { rs[t >> 6] = s; rss[t >> 6] = ss; }
  __syncthreads();
  float S = rs[0] + rs[1] + rs[2] + rs[3];
  float SS = rss[0] + rss[1] + rss[2] + rss[3];
  float mu = S / (float)DMODEL;
  float var = SS / (float)DMODEL - mu * mu;
  float inv = rsqrtf(var + 1e-5f);
  #pragma unroll
  for (int i = 0; i < 4; ++i) {
    int c = t + i * 256;
    float o = (v[i] - mu) * inv * g[c] + b[c];
    hn[(size_t)r * DMODEL + c] = __float2bfloat16(o);
  }
}

// ---------------- GEMM (BT): C[m,n] = sum_k A[m,k] * W[n,k] ----------------
// 128x128 tile, BK=32, 4 waves (2x2 of 64x64), mfma 16x16x32 bf16.
// EPI: 0 = plain store; 1 = softplus(acc + bias[n]); 2 = acc + bias[n] + resid[m,n]
template<int EPI, typename OutT>
__launch_bounds__(256)
__global__ void gemm_bt(int M, int N, int K, int lda, int ldw, int ldc,
                        const __hip_bfloat16* __restrict__ A,
                        const __hip_bfloat16* __restrict__ W,
                        OutT* __restrict__ C,
                        const float* __restrict__ bias,
                        const float* __restrict__ resid, int ldr) {
  __shared__ __align__(16) unsigned short As[128 * 32];
  __shared__ __align__(16) unsigned short Bs[128 * 32];
  const int t = threadIdx.x;
  const int wv = t >> 6, ln = t & 63;
  const int quad = ln >> 4, r16 = ln & 15;
  const int wm = wv >> 1, wn = wv & 1;
  const int tm = blockIdx.y * 128, tn = blockIdx.x * 128;
  const int srow = ln >> 2;        // 0..15
  const int scol = (ln & 3) * 8;   // k element offset

  f32x4 acc[4][4] = {};

  for (int k0 = 0; k0 < K; k0 += 32) {
    __syncthreads();
    #pragma unroll
    for (int p = 0; p < 2; ++p) {
      int ra = p * 64 + wv * 16 + srow;
      const __hip_bfloat16* ga = A + (size_t)(tm + ra) * lda + k0 + scol;
      gll16(ga, &As[ra * 32 + scol]);
      int gn = tn + ra; if (gn > N - 1) gn = N - 1;
      const __hip_bfloat16* gb = W + (size_t)gn * ldw + k0 + scol;
      gll16(gb, &Bs[ra * 32 + scol]);
    }
    __syncthreads();
    bf16x8 af[4], bw[4];
    #pragma unroll
    for (int i = 0; i < 4; ++i)
      af[i] = *(const bf16x8*)&As[(wm * 64 + i * 16 + r16) * 32 + quad * 8];
    #pragma unroll
    for (int j = 0; j < 4; ++j)
      bw[j] = *(const bf16x8*)&Bs[(wn * 64 + j * 16 + r16) * 32 + quad * 8];
    #pragma unroll
    for (int i = 0; i < 4; ++i)
      #pragma unroll
      for (int j = 0; j < 4; ++j)
        acc[i][j] = __builtin_amdgcn_mfma_f32_16x16x32_bf16(af[i], bw[j], acc[i][j], 0, 0, 0);
  }

  #pragma unroll
  for (int i = 0; i < 4; ++i) {
    #pragma unroll
    for (int j = 0; j < 4; ++j) {
      int col = tn + wn * 64 + j * 16 + r16;
      if (col >= N) continue;
      #pragma unroll
      for (int rg = 0; rg < 4; ++rg) {
        int row = tm + wm * 64 + i * 16 + quad * 4 + rg;
        float v = acc[i][j][rg];
        if (EPI == 1) {
          v += bias[col];
          v = (v > 20.f) ? v : log1pf(__expf(v));
        } else if (EPI == 2) {
          v += bias[col] + resid[(size_t)row * ldr + col];
        }
        if constexpr (sizeof(OutT) == 2)
          C[(size_t)row * ldc + col] = __float2bfloat16(v);
        else
          C[(size_t)row * ldc + col] = v;
      }
    }
  }
}

// ---------------- Depthwise causal/anticausal conv + SiLU ----------------
// xz layout: row r = b*L+l, 4096 cols; xr = cols [0,2048), z = cols [2048,4096)
// dir=0 (fwd):  u[l] = silu(cb + sum_j w[j]*xr[l-3+j])
// dir=1 (bwd):  u[l] = silu(cb + sum_j w[j]*xr[l+3-j])
__global__ void conv_silu(const __hip_bfloat16* __restrict__ xz,
                          const float* __restrict__ cw,
                          const float* __restrict__ cb,
                          __hip_bfloat16* __restrict__ u, int dir) {
  const int d = blockIdx.x * 256 + threadIdx.x;  // 0..2047 (gridDim.x = 8)
  const int r = blockIdx.y;                       // 0..4095
  const int b = r >> 11, l = r & (LSEQ - 1);
  float acc = cb[d];
  #pragma unroll
  for (int j = 0; j < DCONV; ++j) {
    int lp = dir ? (l + 3 - j) : (l - 3 + j);
    if (lp >= 0 && lp < LSEQ)
      acc += cw[d * DCONV + j] * bf2f(xz[(size_t)(b * LSEQ + lp) * 4096 + d]);
  }
  float s = acc / (1.f + __expf(-acc));
  u[(size_t)r * DINNER + d] = __float2bfloat16(s);
}

// ---------------- Scan phase 1: per-chunk local state + transition ----------------
// lane layout: n = lane&15, dsub = lane>>4; wave covers 4 d; block (256t) covers 16 d.
// grid: x = DINNER/16 = 128, y = B*NCH = 32
__global__ void scan_p1(const __hip_bfloat16* __restrict__ dt,
                        const __hip_bfloat16* __restrict__ u,
                        const __hip_bfloat16* __restrict__ dbc,
                        const float* __restrict__ A_log,
                        float* __restrict__ hfin, float* __restrict__ Pbuf, int dir) {
  const int t = threadIdx.x;
  const int w = t >> 6, ln = t & 63;
  const int n = ln & 15, dsub = ln >> 4;
  const int d = blockIdx.x * 16 + w * 4 + dsub;
  const int bc = blockIdx.y, b = bc >> 4, c = bc & 15;
  const float A = -__expf(A_log[d * DSTATE + n]);
  float h = 0.f, sdt = 0.f;
  const int s0 = c * CLEN;
  for (int s = 0; s < CLEN; ++s) {
    int lpos = dir ? (LSEQ - 1 - (s0 + s)) : (s0 + s);
    int r = b * LSEQ + lpos;
    float dtv = bf2f(dt[(size_t)r * DINNER + d]);
    float uv  = bf2f(u[(size_t)r * DINNER + d]);
    float Bn  = bf2f(dbc[(size_t)r * 96 + 64 + n]);
    h = __expf(dtv * A) * h + dtv * uv * Bn;
    sdt += dtv;
  }
  const size_t idx = (size_t)((b * NCH + c) * DINNER + d) * DSTATE + n;
  hfin[idx] = h;
  Pbuf[idx] = __expf(A * sdt);
}

// ---------------- Scan phase 2: carry-in + emit gated output ----------------
// g[r,d] = (y + u*D[d]) * silu(z[r,d]),  y = sum_n h*C
__global__ void scan_p2(const __hip_bfloat16* __restrict__ dt,
                        const __hip_bfloat16* __restrict__ u,
                        const __hip_bfloat16* __restrict__ dbc,
                        const float* __restrict__ A_log,
                        const float* __restrict__ Dp,
                        const __hip_bfloat16* __restrict__ xz,
                        const float* __restrict__ hfin, const float* __restrict__ Pbuf,
                        __hip_bfloat16* __restrict__ g, int dir) {
  const int t = threadIdx.x;
  const int w = t >> 6, ln = t & 63;
  const int n = ln & 15, dsub = ln >> 4;
  const int d = blockIdx.x * 16 + w * 4 + dsub;
  const int bc = blockIdx.y, b = bc >> 4, c = bc & 15;
  const float A = -__expf(A_log[d * DSTATE + n]);
  const float Dd = Dp[d];
  // compose carry over preceding chunks (scan order)
  float H = 0.f;
  for (int j = 0; j < c; ++j) {
    size_t idx = (size_t)((b * NCH + j) * DINNER + d) * DSTATE + n;
    H = Pbuf[idx] * H + hfin[idx];
  }
  float h = H;
  const int s0 = c * CLEN;
  for (int s = 0; s < CLEN; ++s) {
    int lpos = dir ? (LSEQ - 1 - (s0 + s)) : (s0 + s);
    int r = b * LSEQ + lpos;
    float dtv = bf2f(dt[(size_t)r * DINNER + d]);
    float uv  = bf2f(u[(size_t)r * DINNER + d]);
    float Bn  = bf2f(dbc[(size_t)r * 96 + 64 + n]);
    float Cn  = bf2f(dbc[(size_t)r * 96 + 80 + n]);
    h = __expf(dtv * A) * h + dtv * uv * Bn;
    float y = h * Cn;
    y += __shfl_xor(y, 1); y += __shfl_xor(y, 2);
    y += __shfl_xor(y, 4); y += __shfl_xor(y, 8);
    if (n == 0) {
      float zv = bf2f(xz[(size_t)r * 4096 + DINNER + d]);
      float sz = zv / (1.f + __expf(-zv));
      g[(size_t)r * DINNER + d] = __float2bfloat16((y + uv * Dd) * sz);
    }
  }
}

// ---------------- launch ----------------
extern "C" void kernel_launch(void* const* d_in, const int* in_sizes, int n_in,
                              void* d_out, int out_size, void* d_ws, size_t ws_size,
                              hipStream_t stream) {
  const float* X   = (const float*)d_in[0];
  const float* LNG = (const float*)d_in[1];
  const float* LNB = (const float*)d_in[2];
  // branch params: base 3 (fwd), base 12 (bwd):
  // +0 in_w, +1 conv_w, +2 conv_b, +3 xproj_w, +4 dt_w, +5 dt_b, +6 A_log, +7 D, +8 out_w
  const float* F[9]; const float* Bp[9];
  for (int i = 0; i < 9; ++i) { F[i] = (const float*)d_in[3 + i]; Bp[i] = (const float*)d_in[12 + i]; }
  const float* PW = (const float*)d_in[21];
  const float* PB = (const float*)d_in[22];
  float* OUT = (float*)d_out;   // reference output dtype is float32

  // workspace carve
  char* w = (char*)d_ws;
  auto carve = [&](size_t bytes) { void* p = (void*)w; w += (bytes + 255) & ~(size_t)255; return p; };
  __hip_bfloat16* hn   = (__hip_bfloat16*)carve((size_t)MROWS * DMODEL * 2);
  __hip_bfloat16* xzf  = (__hip_bfloat16*)carve((size_t)MROWS * 4096 * 2);
  __hip_bfloat16* xzb  = (__hip_bfloat16*)carve((size_t)MROWS * 4096 * 2);
  __hip_bfloat16* uf   = (__hip_bfloat16*)carve((size_t)MROWS * DINNER * 2);
  __hip_bfloat16* ub   = (__hip_bfloat16*)carve((size_t)MROWS * DINNER * 2);
  __hip_bfloat16* dbcf = (__hip_bfloat16*)carve((size_t)MROWS * 96 * 2);
  __hip_bfloat16* dbcb = (__hip_bfloat16*)carve((size_t)MROWS * 96 * 2);
  __hip_bfloat16* dtf  = (__hip_bfloat16*)carve((size_t)MROWS * DINNER * 2);
  __hip_bfloat16* dtb  = (__hip_bfloat16*)carve((size_t)MROWS * DINNER * 2);
  __hip_bfloat16* gf   = (__hip_bfloat16*)carve((size_t)MROWS * DINNER * 2);
  __hip_bfloat16* gb   = (__hip_bfloat16*)carve((size_t)MROWS * DINNER * 2);
  __hip_bfloat16* ycat = (__hip_bfloat16*)carve((size_t)MROWS * DINNER * 2);
  float* hff = (float*)carve((size_t)NBATCH * NCH * DINNER * DSTATE * 4);
  float* pff = (float*)carve((size_t)NBATCH * NCH * DINNER * DSTATE * 4);
  float* hfb = (float*)carve((size_t)NBATCH * NCH * DINNER * DSTATE * 4);
  float* pfb = (float*)carve((size_t)NBATCH * NCH * DINNER * DSTATE * 4);
  // bf16 weight copies
  __hip_bfloat16* w_inf  = (__hip_bfloat16*)carve((size_t)4096 * 1024 * 2);
  __hip_bfloat16* w_inb  = (__hip_bfloat16*)carve((size_t)4096 * 1024 * 2);
  __hip_bfloat16* w_xpf  = (__hip_bfloat16*)carve((size_t)96 * 2048 * 2);
  __hip_bfloat16* w_xpb  = (__hip_bfloat16*)carve((size_t)96 * 2048 * 2);
  __hip_bfloat16* w_dtf  = (__hip_bfloat16*)carve((size_t)2048 * 64 * 2);
  __hip_bfloat16* w_dtb  = (__hip_bfloat16*)carve((size_t)2048 * 64 * 2);
  __hip_bfloat16* w_outf = (__hip_bfloat16*)carve((size_t)1024 * 2048 * 2);
  __hip_bfloat16* w_outb = (__hip_bfloat16*)carve((size_t)1024 * 2048 * 2);
  __hip_bfloat16* w_pj   = (__hip_bfloat16*)carve((size_t)1024 * 2048 * 2);

  // 0. cast weights f32 -> bf16
  auto cast = [&](const float* s, __hip_bfloat16* dst, int n) {
    cast_f2b<<<dim3((n / 4 + 255) / 256), 256, 0, stream>>>(s, dst, n);
  };
  cast(F[0],  w_inf,  4096 * 1024);
  cast(Bp[0], w_inb,  4096 * 1024);
  cast(F[3],  w_xpf,  96 * 2048);
  cast(Bp[3], w_xpb,  96 * 2048);
  cast(F[4],  w_dtf,  2048 * 64);
  cast(Bp[4], w_dtb,  2048 * 64);
  cast(F[8],  w_outf, 1024 * 2048);
  cast(Bp[8], w_outb, 1024 * 2048);
  cast(PW,    w_pj,   1024 * 2048);

  // 1. LayerNorm
  ln_kernel<<<dim3(MROWS), dim3(256), 0, stream>>>(X, LNG, LNB, hn);

  // 2. xz = hn @ in_w^T   (per branch)
  gemm_bt<0, __hip_bfloat16><<<dim3(32, 32), 256, 0, stream>>>(MROWS, 4096, 1024, 1024, 1024, 4096,
                                               hn, w_inf, xzf, nullptr, nullptr, 0);
  gemm_bt<0, __hip_bfloat16><<<dim3(32, 32), 256, 0, stream>>>(MROWS, 4096, 1024, 1024, 1024, 4096,
                                               hn, w_inb, xzb, nullptr, nullptr, 0);

  // 3. depthwise conv + silu -> u
  conv_silu<<<dim3(8, MROWS), 256, 0, stream>>>(xzf, F[1], F[2], uf, 0);
  conv_silu<<<dim3(8, MROWS), 256, 0, stream>>>(xzb, Bp[1], Bp[2], ub, 1);

  // 4. dbc = u @ xproj^T  (N=96)
  gemm_bt<0, __hip_bfloat16><<<dim3(1, 32), 256, 0, stream>>>(MROWS, 96, 2048, 2048, 2048, 96,
                                              uf, w_xpf, dbcf, nullptr, nullptr, 0);
  gemm_bt<0, __hip_bfloat16><<<dim3(1, 32), 256, 0, stream>>>(MROWS, 96, 2048, 2048, 2048, 96,
                                              ub, w_xpb, dbcb, nullptr, nullptr, 0);

  // 5. dt = softplus(dbc[:, :64] @ dt_w^T + dt_b)
  gemm_bt<1, __hip_bfloat16><<<dim3(16, 32), 256, 0, stream>>>(MROWS, 2048, 64, 96, 64, 2048,
                                               dbcf, w_dtf, dtf, F[5], nullptr, 0);
  gemm_bt<1, __hip_bfloat16><<<dim3(16, 32), 256, 0, stream>>>(MROWS, 2048, 64, 96, 64, 2048,
                                               dbcb, w_dtb, dtb, Bp[5], nullptr, 0);

  // 6. scan phase 1
  scan_p1<<<dim3(128, 32), 256, 0, stream>>>(dtf, uf, dbcf, F[6], hff, pff, 0);
  scan_p1<<<dim3(128, 32), 256, 0, stream>>>(dtb, ub, dbcb, Bp[6], hfb, pfb, 1);

  // 7. scan phase 2 (fused D-skip + silu(z) gating) -> g
  scan_p2<<<dim3(128, 32), 256, 0, stream>>>(dtf, uf, dbcf, F[6], F[7], xzf, hff, pff, gf, 0);
  scan_p2<<<dim3(128, 32), 256, 0, stream>>>(dtb, ub, dbcb, Bp[6], Bp[7], xzb, hfb, pfb, gb, 1);

  // 8. per-branch out-proj into concat buffer (cols [0,1024) fwd, [1024,2048) bwd)
  gemm_bt<0, __hip_bfloat16><<<dim3(8, 32), 256, 0, stream>>>(MROWS, 1024, 2048, 2048, 2048, 2048,
                                              gf, w_outf, ycat, nullptr, nullptr, 0);
  gemm_bt<0, __hip_bfloat16><<<dim3(8, 32), 256, 0, stream>>>(MROWS, 1024, 2048, 2048, 2048, 2048,
                                              gb, w_outb, ycat + 1024, nullptr, nullptr, 0);

  // 9. out = x + ycat @ proj^T + proj_b   (float32 output)
  gemm_bt<2, float><<<dim3(8, 32), 256, 0, stream>>>(MROWS, 1024, 2048, 2048, 2048, 1024,
                                              ycat, w_pj, OUT, PB, X, 1024);
}

// Round 4
// 732.348 us; speedup vs baseline: 1.8549x; 1.8549x over previous
//
#include <hip/hip_runtime.h>
#include <hip/hip_bf16.h>
#include <cstdint>
#include <cstddef>

// Problem constants
#define DMODEL 1024
#define DINNER 2048
#define DSTATE 16
#define DCONV  4
#define DTRANK 64
#define NBATCH 2
#define LSEQ   2048
#define MROWS  (NBATCH*LSEQ)   // 4096

// Scan chunking
#define NCH  32
#define CLEN 64
#define TSTEP 16   // steps per LDS tile

typedef __bf16 bf16x8 __attribute__((ext_vector_type(8)));
typedef float  f32x4  __attribute__((ext_vector_type(4)));

__device__ __forceinline__ float bf2f(__hip_bfloat16 v) { return __bfloat162float(v); }

__device__ __forceinline__ void gll16(const void* g, void* l) {
  __builtin_amdgcn_global_load_lds((const __attribute__((address_space(1))) void*)g,
                                   (__attribute__((address_space(3))) void*)l, 16, 0, 0);
}

// ---------------- f32 -> bf16 cast (weights) ----------------
__global__ void cast_f2b(const float* __restrict__ src, __hip_bfloat16* __restrict__ dst, int n) {
  int i = (blockIdx.x * 256 + threadIdx.x) * 4;
  if (i + 3 < n) {
    float4 v = *(const float4*)(src + i);
    dst[i + 0] = __float2bfloat16(v.x);
    dst[i + 1] = __float2bfloat16(v.y);
    dst[i + 2] = __float2bfloat16(v.z);
    dst[i + 3] = __float2bfloat16(v.w);
  } else {
    for (int j = i; j < n; ++j) dst[j] = __float2bfloat16(src[j]);
  }
}

// ---------------- LayerNorm: x (4096x1024 f32) -> hn (bf16) ----------------
__global__ void ln_kernel(const float* __restrict__ x,
                          const float* __restrict__ g,
                          const float* __restrict__ b,
                          __hip_bfloat16* __restrict__ hn) {
  const int r = blockIdx.x;
  const int t = threadIdx.x;           // 256 threads
  float v[4];
  float s = 0.f, ss = 0.f;
  #pragma unroll
  for (int i = 0; i < 4; ++i) {
    v[i] = x[(size_t)r * DMODEL + t + i * 256];
    s += v[i]; ss += v[i] * v[i];
  }
  #pragma unroll
  for (int o = 32; o >= 1; o >>= 1) { s += __shfl_xor(s, o); ss += __shfl_xor(ss, o); }
  __shared__ float rs[4], rss[4];
  if ((t & 63) == 0) { rs[t >> 6] = s; rss[t >> 6] = ss; }
  __syncthreads();
  float S = rs[0] + rs[1] + rs[2] + rs[3];
  float SS = rss[0] + rss[1] + rss[2] + rss[3];
  float mu = S / (float)DMODEL;
  float var = SS / (float)DMODEL - mu * mu;
  float inv = rsqrtf(var + 1e-5f);
  #pragma unroll
  for (int i = 0; i < 4; ++i) {
    int c = t + i * 256;
    float o = (v[i] - mu) * inv * g[c] + b[c];
    hn[(size_t)r * DMODEL + c] = __float2bfloat16(o);
  }
}

// ---------------- GEMM (BT): C[m,n] = sum_k A[m,k] * W[n,k] ----------------
// 128x128 tile, BK=32, 4 waves (2x2 of 64x64), mfma 16x16x32 bf16.
// EPI: 0 = plain store; 1 = softplus(acc + bias[n]); 2 = acc + bias[n] + resid[m,n];
//      3 = split-K atomicAdd into f32 C
template<int EPI, typename OutT>
__launch_bounds__(256)
__global__ void gemm_bt(int M, int N, int kbeg, int kend, int lda, int ldw, int ldc,
                        const __hip_bfloat16* __restrict__ A,
                        const __hip_bfloat16* __restrict__ W,
                        OutT* __restrict__ C,
                        const float* __restrict__ bias,
                        const float* __restrict__ resid, int ldr) {
  __shared__ __align__(16) unsigned short As[128 * 32];
  __shared__ __align__(16) unsigned short Bs[128 * 32];
  const int t = threadIdx.x;
  const int wv = t >> 6, ln = t & 63;
  const int quad = ln >> 4, r16 = ln & 15;
  const int wm = wv >> 1, wn = wv & 1;
  const int tm = blockIdx.y * 128, tn = blockIdx.x * 128;
  const int kb = kbeg + blockIdx.z * (kend - kbeg);   // z slices assume uniform span
  const int ke = kb + (kend - kbeg);
  const int srow = ln >> 2;        // 0..15
  const int scol = (ln & 3) * 8;   // k element offset

  f32x4 acc[4][4] = {};

  for (int k0 = kb; k0 < ke; k0 += 32) {
    __syncthreads();
    #pragma unroll
    for (int p = 0; p < 2; ++p) {
      int ra = p * 64 + wv * 16 + srow;
      const __hip_bfloat16* ga = A + (size_t)(tm + ra) * lda + k0 + scol;
      gll16(ga, &As[ra * 32 + scol]);
      int gn = tn + ra; if (gn > N - 1) gn = N - 1;
      const __hip_bfloat16* gb = W + (size_t)gn * ldw + k0 + scol;
      gll16(gb, &Bs[ra * 32 + scol]);
    }
    __syncthreads();
    bf16x8 af[4], bw[4];
    #pragma unroll
    for (int i = 0; i < 4; ++i)
      af[i] = *(const bf16x8*)&As[(wm * 64 + i * 16 + r16) * 32 + quad * 8];
    #pragma unroll
    for (int j = 0; j < 4; ++j)
      bw[j] = *(const bf16x8*)&Bs[(wn * 64 + j * 16 + r16) * 32 + quad * 8];
    #pragma unroll
    for (int i = 0; i < 4; ++i)
      #pragma unroll
      for (int j = 0; j < 4; ++j)
        acc[i][j] = __builtin_amdgcn_mfma_f32_16x16x32_bf16(af[i], bw[j], acc[i][j], 0, 0, 0);
  }

  #pragma unroll
  for (int i = 0; i < 4; ++i) {
    #pragma unroll
    for (int j = 0; j < 4; ++j) {
      int col = tn + wn * 64 + j * 16 + r16;
      if (col >= N) continue;
      #pragma unroll
      for (int rg = 0; rg < 4; ++rg) {
        int row = tm + wm * 64 + i * 16 + quad * 4 + rg;
        float v = acc[i][j][rg];
        if (EPI == 1) {
          v += bias[col];
          v = (v > 20.f) ? v : log1pf(__expf(v));
        } else if (EPI == 2) {
          v += bias[col] + resid[(size_t)row * ldr + col];
        }
        if constexpr (EPI == 3) {
          atomicAdd((float*)&C[(size_t)row * ldc + col], v);
        } else if constexpr (sizeof(OutT) == 2) {
          C[(size_t)row * ldc + col] = __float2bfloat16(v);
        } else {
          C[(size_t)row * ldc + col] = v;
        }
      }
    }
  }
}

// ---------------- f32 -> bf16 finish for split-K output ----------------
__global__ void finish_cast(const float* __restrict__ src, __hip_bfloat16* __restrict__ dst, int n) {
  int i = blockIdx.x * 256 + threadIdx.x;
  if (i < n) dst[i] = __float2bfloat16(src[i]);
}

// ---------------- Depthwise conv + SiLU (merged dirs) ----------------
// xz [4096][8192]: dir half at col dir*4096; xr = +0..2047, z = +2048..4095
// u [2][4096][2048]
__global__ void conv_silu(const __hip_bfloat16* __restrict__ xz,
                          const float* __restrict__ cwf, const float* __restrict__ cbf,
                          const float* __restrict__ cwb, const float* __restrict__ cbb,
                          __hip_bfloat16* __restrict__ u) {
  const int d   = blockIdx.x * 256 + threadIdx.x;   // 0..2047 (grid.x=8)
  const int b   = blockIdx.y >> 8;                  // grid.y = 512
  const int rb  = blockIdx.y & 255;
  const int dir = blockIdx.z;                       // grid.z = 2
  const int l0  = rb * 8;
  const float* cw = dir ? cwb : cwf;
  const float* cb = dir ? cbb : cbf;
  float w0 = cw[d * 4 + 0], w1 = cw[d * 4 + 1], w2 = cw[d * 4 + 2], w3 = cw[d * 4 + 3];
  float bias = cb[d];
  const size_t colbase = (size_t)dir * 4096 + d;
  float xv[11];
  #pragma unroll
  for (int j = 0; j < 11; ++j) {
    int l = dir ? (l0 + j) : (l0 - 3 + j);
    xv[j] = (l >= 0 && l < LSEQ) ? bf2f(xz[(size_t)(b * LSEQ + l) * 8192 + colbase]) : 0.f;
  }
  __hip_bfloat16* uo = u + (size_t)dir * MROWS * DINNER;
  #pragma unroll
  for (int s = 0; s < 8; ++s) {
    float acc;
    if (dir)
      acc = bias + w0 * xv[s + 3] + w1 * xv[s + 2] + w2 * xv[s + 1] + w3 * xv[s];
    else
      acc = bias + w0 * xv[s] + w1 * xv[s + 1] + w2 * xv[s + 2] + w3 * xv[s + 3];
    float sv = acc / (1.f + __expf(-acc));
    uo[(size_t)(b * LSEQ + l0 + s) * DINNER + d] = __float2bfloat16(sv);
  }
}

// ---------------- Scan phase 1: per-chunk local states (registers) ----------------
// grid (8, 128): y = (dir*2+b)*NCH + c ; thread -> one d, 16 states in regs
__global__ __launch_bounds__(256)
void scan_p1(const __hip_bfloat16* __restrict__ dt,
             const __hip_bfloat16* __restrict__ u,
             const __hip_bfloat16* __restrict__ dbc,
             const float* __restrict__ alogf, const float* __restrict__ alogb,
             float* __restrict__ hfin, float* __restrict__ sdtbuf) {
  const int d = blockIdx.x * 256 + threadIdx.x;
  const int y = blockIdx.y;
  const int c = y & (NCH - 1), b = (y >> 5) & 1, dir = y >> 6;
  const float* alog = dir ? alogb : alogf;
  const __hip_bfloat16* dtp = dt + (size_t)dir * MROWS * DINNER;
  const __hip_bfloat16* up  = u  + (size_t)dir * MROWS * DINNER;
  const __hip_bfloat16* dbp = dbc + (size_t)dir * MROWS * 96;

  float A[DSTATE];
  #pragma unroll
  for (int n = 0; n < DSTATE; ++n) A[n] = -__expf(alog[d * DSTATE + n]);

  __shared__ float Bs[TSTEP][DSTATE];
  float h[DSTATE] = {};
  float sdt = 0.f;

  for (int tile = 0; tile < CLEN / TSTEP; ++tile) {
    __syncthreads();
    {  // stage B rows (one elem per thread)
      int sl = threadIdx.x >> 4, k = threadIdx.x & 15;
      int step = c * CLEN + tile * TSTEP + sl;
      int lpos = dir ? (LSEQ - 1 - step) : step;
      Bs[sl][k] = bf2f(dbp[(size_t)(b * LSEQ + lpos) * 96 + 64 + k]);
    }
    __syncthreads();
    #pragma unroll
    for (int s = 0; s < TSTEP; ++s) {
      int step = c * CLEN + tile * TSTEP + s;
      int lpos = dir ? (LSEQ - 1 - step) : step;
      size_t r = (size_t)(b * LSEQ + lpos);
      float dtv = bf2f(dtp[r * DINNER + d]);
      float uv  = bf2f(up[r * DINNER + d]);
      float du = dtv * uv;
      #pragma unroll
      for (int n = 0; n < DSTATE; ++n)
        h[n] = __expf(dtv * A[n]) * h[n] + du * Bs[s][n];
      sdt += dtv;
    }
  }
  float* hp = hfin + ((size_t)y * DINNER + d) * DSTATE;
  #pragma unroll
  for (int q = 0; q < 4; ++q)
    *(f32x4*)(hp + q * 4) = f32x4{h[q * 4], h[q * 4 + 1], h[q * 4 + 2], h[q * 4 + 3]};
  sdtbuf[(size_t)y * DINNER + d] = sdt;
}

// ---------------- Prefix over chunks: exclusive carry states ----------------
// threads = dir(2) x b(2) x d(2048) x n(16) = 131072
__global__ void scan_prefix(const float* __restrict__ hfin, const float* __restrict__ sdtbuf,
                            const float* __restrict__ alogf, const float* __restrict__ alogb,
                            float* __restrict__ Hstart) {
  int g = blockIdx.x * 256 + threadIdx.x;
  int n = g & 15, d = (g >> 4) & 2047, b = (g >> 15) & 1, dir = (g >> 16) & 1;
  const float* alog = dir ? alogb : alogf;
  float A = -__expf(alog[d * DSTATE + n]);
  float H = 0.f;
  for (int c = 0; c < NCH; ++c) {
    int y = (dir * 2 + b) * NCH + c;
    size_t idx = ((size_t)y * DINNER + d) * DSTATE + n;
    Hstart[idx] = H;
    float P = __expf(A * sdtbuf[(size_t)y * DINNER + d]);
    H = P * H + hfin[idx];
  }
}

// ---------------- Scan phase 2: emit gated output ----------------
__global__ __launch_bounds__(256)
void scan_p2(const __hip_bfloat16* __restrict__ dt,
             const __hip_bfloat16* __restrict__ u,
             const __hip_bfloat16* __restrict__ dbc,
             const float* __restrict__ alogf, const float* __restrict__ alogb,
             const float* __restrict__ Dpf, const float* __restrict__ Dpb,
             const __hip_bfloat16* __restrict__ xz,
             const float* __restrict__ Hstart,
             __hip_bfloat16* __restrict__ gout) {
  const int d = blockIdx.x * 256 + threadIdx.x;
  const int y = blockIdx.y;
  const int c = y & (NCH - 1), b = (y >> 5) & 1, dir = y >> 6;
  const float* alog = dir ? alogb : alogf;
  const float Dd = dir ? Dpb[d] : Dpf[d];
  const __hip_bfloat16* dtp = dt + (size_t)dir * MROWS * DINNER;
  const __hip_bfloat16* up  = u  + (size_t)dir * MROWS * DINNER;
  const __hip_bfloat16* dbp = dbc + (size_t)dir * MROWS * 96;
  __hip_bfloat16* gp = gout + (size_t)dir * MROWS * DINNER;
  const size_t zcol = (size_t)dir * 4096 + 2048 + d;

  float A[DSTATE];
  #pragma unroll
  for (int n = 0; n < DSTATE; ++n) A[n] = -__expf(alog[d * DSTATE + n]);

  float h[DSTATE];
  {
    const float* hp = Hstart + ((size_t)y * DINNER + d) * DSTATE;
    #pragma unroll
    for (int q = 0; q < 4; ++q) {
      f32x4 v = *(const f32x4*)(hp + q * 4);
      h[q * 4] = v.x; h[q * 4 + 1] = v.y; h[q * 4 + 2] = v.z; h[q * 4 + 3] = v.w;
    }
  }

  __shared__ float BCs[TSTEP][32];   // [s][0..15]=B, [s][16..31]=C

  for (int tile = 0; tile < CLEN / TSTEP; ++tile) {
    __syncthreads();
    {  // stage B+C rows: 512 f32, 2 per thread
      #pragma unroll
      for (int e = 0; e < 2; ++e) {
        int id = threadIdx.x + e * 256;
        int sl = id >> 5, kk = id & 31;
        int step = c * CLEN + tile * TSTEP + sl;
        int lpos = dir ? (LSEQ - 1 - step) : step;
        BCs[sl][kk] = bf2f(dbp[(size_t)(b * LSEQ + lpos) * 96 + 64 + kk]);
      }
    }
    __syncthreads();
    #pragma unroll
    for (int s = 0; s < TSTEP; ++s) {
      int step = c * CLEN + tile * TSTEP + s;
      int lpos = dir ? (LSEQ - 1 - step) : step;
      size_t r = (size_t)(b * LSEQ + lpos);
      float dtv = bf2f(dtp[r * DINNER + d]);
      float uv  = bf2f(up[r * DINNER + d]);
      float du = dtv * uv;
      float y0 = 0.f, y1 = 0.f, y2 = 0.f, y3 = 0.f;
      #pragma unroll
      for (int n = 0; n < DSTATE; n += 4) {
        h[n]   = __expf(dtv * A[n])   * h[n]   + du * BCs[s][n];
        h[n+1] = __expf(dtv * A[n+1]) * h[n+1] + du * BCs[s][n+1];
        h[n+2] = __expf(dtv * A[n+2]) * h[n+2] + du * BCs[s][n+2];
        h[n+3] = __expf(dtv * A[n+3]) * h[n+3] + du * BCs[s][n+3];
        y0 += h[n]   * BCs[s][16 + n];
        y1 += h[n+1] * BCs[s][16 + n + 1];
        y2 += h[n+2] * BCs[s][16 + n + 2];
        y3 += h[n+3] * BCs[s][16 + n + 3];
      }
      float yv = (y0 + y1) + (y2 + y3) + uv * Dd;
      float zv = bf2f(xz[r * 8192 + zcol]);
      float sz = zv / (1.f + __expf(-zv));
      gp[r * DINNER + d] = __float2bfloat16(yv * sz);
    }
  }
}

// ---------------- launch ----------------
extern "C" void kernel_launch(void* const* d_in, const int* in_sizes, int n_in,
                              void* d_out, int out_size, void* d_ws, size_t ws_size,
                              hipStream_t stream) {
  const float* X   = (const float*)d_in[0];
  const float* LNG = (const float*)d_in[1];
  const float* LNB = (const float*)d_in[2];
  const float* F[9]; const float* Bp[9];
  for (int i = 0; i < 9; ++i) { F[i] = (const float*)d_in[3 + i]; Bp[i] = (const float*)d_in[12 + i]; }
  const float* PW = (const float*)d_in[21];
  const float* PB = (const float*)d_in[22];
  float* OUT = (float*)d_out;   // f32 output

  char* w = (char*)d_ws;
  auto carve = [&](size_t bytes) { void* p = (void*)w; w += (bytes + 255) & ~(size_t)255; return p; };
  __hip_bfloat16* hn   = (__hip_bfloat16*)carve((size_t)MROWS * DMODEL * 2);
  __hip_bfloat16* xz   = (__hip_bfloat16*)carve((size_t)MROWS * 8192 * 2);
  __hip_bfloat16* ubuf = (__hip_bfloat16*)carve((size_t)2 * MROWS * DINNER * 2);
  float*          dbcf = (float*)carve((size_t)2 * MROWS * 96 * 4);
  __hip_bfloat16* dbcb = (__hip_bfloat16*)carve((size_t)2 * MROWS * 96 * 2);
  __hip_bfloat16* dtb  = (__hip_bfloat16*)carve((size_t)2 * MROWS * DINNER * 2);
  __hip_bfloat16* gbuf = (__hip_bfloat16*)carve((size_t)2 * MROWS * DINNER * 2);
  __hip_bfloat16* ycat = (__hip_bfloat16*)carve((size_t)MROWS * DINNER * 2);
  float* hfin   = (float*)carve((size_t)128 * DINNER * DSTATE * 4);
  float* sdtbuf = (float*)carve((size_t)128 * DINNER * 4);
  float* Hstart = (float*)carve((size_t)128 * DINNER * DSTATE * 4);
  __hip_bfloat16* wcat  = (__hip_bfloat16*)carve((size_t)8192 * 1024 * 2);
  __hip_bfloat16* wxp   = (__hip_bfloat16*)carve((size_t)2 * 96 * 2048 * 2);
  __hip_bfloat16* wdt   = (__hip_bfloat16*)carve((size_t)2 * 2048 * 64 * 2);
  __hip_bfloat16* wout  = (__hip_bfloat16*)carve((size_t)2 * 1024 * 2048 * 2);
  __hip_bfloat16* wpj   = (__hip_bfloat16*)carve((size_t)1024 * 2048 * 2);

  auto cast = [&](const float* s, __hip_bfloat16* dst, int n) {
    cast_f2b<<<dim3((n / 4 + 255) / 256), 256, 0, stream>>>(s, dst, n);
  };
  cast(F[0],  wcat,                 4096 * 1024);
  cast(Bp[0], wcat + 4096 * 1024,   4096 * 1024);
  cast(F[3],  wxp,                  96 * 2048);
  cast(Bp[3], wxp + 96 * 2048,      96 * 2048);
  cast(F[4],  wdt,                  2048 * 64);
  cast(Bp[4], wdt + 2048 * 64,      2048 * 64);
  cast(F[8],  wout,                 1024 * 2048);
  cast(Bp[8], wout + 1024 * 2048,   1024 * 2048);
  cast(PW,    wpj,                  1024 * 2048);

  hipMemsetAsync(dbcf, 0, (size_t)2 * MROWS * 96 * 4, stream);

  // 1. LayerNorm
  ln_kernel<<<dim3(MROWS), 256, 0, stream>>>(X, LNG, LNB, hn);

  // 2. xz = hn @ [in_w_f ; in_w_b]^T  (N=8192, one dispatch)
  gemm_bt<0, __hip_bfloat16><<<dim3(64, 32), 256, 0, stream>>>(
      MROWS, 8192, 0, 1024, 1024, 1024, 8192, hn, wcat, xz, nullptr, nullptr, 0);

  // 3. conv + silu -> u   (merged dirs)
  conv_silu<<<dim3(8, 512, 2), 256, 0, stream>>>(xz, F[1], F[2], Bp[1], Bp[2], ubuf);

  // 4. dbc = u @ xproj^T  (split-K=8, f32 atomics), per dir
  for (int dir = 0; dir < 2; ++dir)
    gemm_bt<3, float><<<dim3(1, 32, 8), 256, 0, stream>>>(
        MROWS, 96, 0, 256, 2048, 2048, 96,
        ubuf + (size_t)dir * MROWS * DINNER, wxp + (size_t)dir * 96 * 2048,
        dbcf + (size_t)dir * MROWS * 96, nullptr, nullptr, 0);
  finish_cast<<<dim3((2 * MROWS * 96 + 255) / 256), 256, 0, stream>>>(
      dbcf, dbcb, 2 * MROWS * 96);

  // 5. dt = softplus(dbc[:, :64] @ dt_w^T + dt_b), per dir
  for (int dir = 0; dir < 2; ++dir)
    gemm_bt<1, __hip_bfloat16><<<dim3(16, 32), 256, 0, stream>>>(
        MROWS, 2048, 0, 64, 96, 64, 2048,
        dbcb + (size_t)dir * MROWS * 96, wdt + (size_t)dir * 2048 * 64,
        dtb + (size_t)dir * MROWS * DINNER, dir ? Bp[5] : F[5], nullptr, 0);

  // 6. scan phase 1 (both dirs in one dispatch)
  scan_p1<<<dim3(8, 128), 256, 0, stream>>>(dtb, ubuf, dbcb, F[6], Bp[6], hfin, sdtbuf);

  // 7. chunk-prefix carries
  scan_prefix<<<dim3(512), 256, 0, stream>>>(hfin, sdtbuf, F[6], Bp[6], Hstart);

  // 8. scan phase 2 -> gated g
  scan_p2<<<dim3(8, 128), 256, 0, stream>>>(dtb, ubuf, dbcb, F[6], Bp[6], F[7], Bp[7],
                                            xz, Hstart, gbuf);

  // 9. out-proj per dir into concat halves
  for (int dir = 0; dir < 2; ++dir)
    gemm_bt<0, __hip_bfloat16><<<dim3(8, 32), 256, 0, stream>>>(
        MROWS, 1024, 0, 2048, 2048, 2048, 2048,
        gbuf + (size_t)dir * MROWS * DINNER, wout + (size_t)dir * 1024 * 2048,
        ycat + dir * 1024, nullptr, nullptr, 0);

  // 10. out = x + ycat @ proj^T + proj_b   (f32 out)
  gemm_bt<2, float><<<dim3(8, 32), 256, 0, stream>>>(
      MROWS, 1024, 0, 2048, 2048, 2048, 1024, ycat, wpj, OUT, PB, X, 1024);
}